// Round 1
// baseline (665.444 us; speedup 1.0000x reference)
//
#include <hip/hip_runtime.h>
#include <hip/hip_bf16.h>

#define DD 128
#define KK 256
#define TS 128      // samples per stage-3 tile
#define ROWB 136    // padded LDS row stride (bf16 elems): 128 + 8 breaks b128 phase conflicts

typedef __attribute__((ext_vector_type(8))) short short8;
typedef __attribute__((ext_vector_type(4))) float f32x4;

static __device__ __forceinline__ unsigned short f2bf(float f) {
    unsigned int u = __float_as_uint(f);
    unsigned int r = (u + 0x7fffu + ((u >> 16) & 1u)) >> 16;   // RNE
    return (unsigned short)r;
}

// ---------------- stage 1: per-block centroid partial sums + ||x||^2 ----------------
__global__ __launch_bounds__(1024, 1) void k_stage1(
    const float* __restrict__ X, const int* __restrict__ labels,
    float* __restrict__ partial, float* __restrict__ x2g,
    int spb, int merge_atomic)
{
    __shared__ float sums[KK * DD];   // 131072 B (gfx950 allows 160 KiB/workgroup)
    const int tid = threadIdx.x;
    for (int i = tid; i < KK * DD; i += 1024) sums[i] = 0.f;
    __syncthreads();

    const int lane = tid & 63;
    const int wave = tid >> 6;
    const int base = blockIdx.x * spb;
#pragma unroll 4
    for (int s = wave; s < spb; s += 16) {
        const int n = base + s;
        const float2 v = *(const float2*)(X + (size_t)n * DD + 2 * lane); // coalesced 512B/wave
        float p = v.x * v.x + v.y * v.y;
#pragma unroll
        for (int m = 32; m > 0; m >>= 1) p += __shfl_xor(p, m);
        if (lane == 0) x2g[n] = p;
        const int l = labels[n];
        atomicAdd(&sums[l * DD + 2 * lane], v.x);      // LDS atomics, no intra-wave conflict
        atomicAdd(&sums[l * DD + 2 * lane + 1], v.y);
    }
    __syncthreads();

    if (merge_atomic) {
        for (int i = tid; i < KK * DD; i += 1024) atomicAdd(&partial[i], sums[i]);
    } else {
        float* dst = partial + (size_t)blockIdx.x * (KK * DD);
        for (int i = tid; i < KK * DD; i += 1024) dst[i] = sums[i];
    }
}

// ---------------- stage 2: reduce partials, normalize (counts cancel), emit bf16 ----------------
__global__ void k_stage2(const float* __restrict__ partial, int nparts,
                         unsigned short* __restrict__ centb)
{
    const int k = blockIdx.x;
    const int d = threadIdx.x;   // 128 threads
    float s = 0.f;
    for (int b = 0; b < nparts; ++b)
        s += partial[(size_t)b * (KK * DD) + k * DD + d];
    float sq = s * s;
#pragma unroll
    for (int m = 32; m > 0; m >>= 1) sq += __shfl_xor(sq, m);
    __shared__ float wsum[2];
    if ((d & 63) == 0) wsum[d >> 6] = sq;
    __syncthreads();
    const float inv = rsqrtf(wsum[0] + wsum[1]);
    centb[k * DD + d] = f2bf(s * inv);
}

// ---------------- stage 3: fused X@C^T (bf16 MFMA) + pos/neg loss + reduction ----------------
__global__ __launch_bounds__(512, 1) void k_stage3(
    const float* __restrict__ X, const int* __restrict__ labels,
    const float* __restrict__ x2g, const unsigned short* __restrict__ centb,
    const float* __restrict__ hbias, float* __restrict__ loss, int spb)
{
    __shared__ unsigned short Cl[KK * ROWB];  // 69632 B, row = cluster (B^T layout)
    __shared__ unsigned short Xl[TS * ROWB];  // 34816 B, row = sample
    __shared__ int   labs[TS];
    __shared__ float x2s[TS];
    __shared__ float lred[16];

    const int tid = threadIdx.x;
    const float hb = *hbias;
    const float bias = (hb > 20.f) ? hb : log1pf(__expf(hb));
    const float pos_bias = bias;
    const float neg_bias = 9.f * bias + 0.05f;

    // stage all centroids once per block (16B chunks)
    const uint4* csrc = (const uint4*)centb;
    for (int c = tid; c < KK * DD / 8; c += 512) {
        const int row = c >> 4;
        const int col = (c & 15) << 3;
        const uint4 v = csrc[c];
        *(uint4*)(&Cl[row * ROWB + col]) = v;
    }

    const int lane = tid & 63;
    const int wave = tid >> 6;
    const int m15  = lane & 15;
    const int q    = lane >> 4;
    const int kq   = q << 3;
    const int base = blockIdx.x * spb;
    float pos_acc = 0.f, neg_acc = 0.f;

    for (int t0 = 0; t0 < spb; t0 += TS) {
        __syncthreads();  // protects Xl reuse (and covers Cl staging on iter 0)
        // stage X tile: TS*DD fp32 -> bf16 LDS (each thread: 8 float4 loads)
        const float4* xsrc = (const float4*)(X + (size_t)(base + t0) * DD);
        for (int c = tid; c < TS * DD / 4; c += 512) {
            const int row = c >> 5;
            const int col = (c & 31) << 2;
            const float4 v = xsrc[c];
            ushort4 pk = make_ushort4(f2bf(v.x), f2bf(v.y), f2bf(v.z), f2bf(v.w));
            *(ushort4*)(&Xl[row * ROWB + col]) = pk;
        }
        if (tid < TS) {
            labs[tid] = labels[base + t0 + tid];
            x2s[tid]  = x2g[base + t0 + tid];
        }
        __syncthreads();

        // wave computes its 16 samples x 256 clusters
        short8 afrag[4];
        const int arow = (wave << 4) + m15;      // A[m=lane&15][k=q*8+j]
#pragma unroll
        for (int s = 0; s < 4; ++s)
            afrag[s] = *(const short8*)(&Xl[arow * ROWB + (s << 5) + kq]);

        f32x4 acc[16];
#pragma unroll
        for (int t = 0; t < 16; ++t) acc[t] = (f32x4){0.f, 0.f, 0.f, 0.f};

#pragma unroll
        for (int t = 0; t < 16; ++t) {
            const int brow = (t << 4) + m15;     // B^T row = cluster
#pragma unroll
            for (int s = 0; s < 4; ++s) {
                const short8 bfrag = *(const short8*)(&Cl[brow * ROWB + (s << 5) + kq]);
                acc[t] = __builtin_amdgcn_mfma_f32_16x16x32_bf16(afrag[s], bfrag, acc[t], 0, 0, 0);
            }
        }

        // epilogue: D layout col=lane&15 (cluster), row=q*4+r (sample)
#pragma unroll
        for (int r = 0; r < 4; ++r) {
            const int ml = (wave << 4) + (q << 2) + r;
            const int l  = labs[ml];
            const float x2 = x2s[ml];
            float posd = -1e30f, negd = -1e30f;
#pragma unroll
            for (int t = 0; t < 16; ++t) {
                const int cl = (t << 4) + m15;
                const float v = acc[t][r];
                const bool isp = (cl == l);
                posd = isp ? v : posd;
                negd = isp ? negd : fmaxf(negd, v);
            }
#pragma unroll
            for (int m = 1; m < 16; m <<= 1) {   // reduce across the 16 lanes of this row-group
                posd = fmaxf(posd, __shfl_xor(posd, m));
                negd = fmaxf(negd, __shfl_xor(negd, m));
            }
            if (m15 == 0) {
                const float pd = x2 + 1.0f - 2.f * posd;  // c2 == 1 (normalized)
                const float nd = x2 + 1.0f - 2.f * negd;  // min dist <=> max dot
                pos_acc += fmaxf(pd - pos_bias, 0.f);
                neg_acc += fmaxf(neg_bias - nd, 0.f);
            }
        }
    }

#pragma unroll
    for (int m = 32; m > 0; m >>= 1) {
        pos_acc += __shfl_xor(pos_acc, m);
        neg_acc += __shfl_xor(neg_acc, m);
    }
    if (lane == 0) { lred[wave] = pos_acc; lred[8 + wave] = neg_acc; }
    __syncthreads();
    if (tid == 0) {
        float p = 0.f, n = 0.f;
#pragma unroll
        for (int w = 0; w < 8; ++w) { p += lred[w]; n += lred[8 + w]; }
        atomicAdd(&loss[0], p);
        atomicAdd(&loss[1], n);
    }
}

__global__ void k_final(const float* __restrict__ loss, float* __restrict__ out, float invN)
{
    if (threadIdx.x == 0) {
        out[0] = 4.0f * loss[0] * invN;
        out[1] = loss[1] * invN;
    }
}

extern "C" void kernel_launch(void* const* d_in, const int* in_sizes, int n_in,
                              void* d_out, int out_size, void* d_ws, size_t ws_size,
                              hipStream_t stream)
{
    const float* X      = (const float*)d_in[0];
    // d_in[1] (scores) is unused by the reference forward — never read it.
    const int*   labels = (const int*)d_in[2];
    const float* hbias  = (const float*)d_in[3];
    float* out = (float*)d_out;
    const int N = in_sizes[0] / DD;

    char* ws = (char*)d_ws;
    float* loss           = (float*)ws;                                    // 2 floats (256B pad)
    float* x2g            = (float*)(ws + 256);                            // N floats
    unsigned short* centb = (unsigned short*)(ws + 256 + (size_t)N * 4);   // K*D bf16
    float* partial        = (float*)(ws + 256 + (size_t)N * 4 + (size_t)KK * DD * 2);

    const int B1 = 256;
    const int spb1 = N / B1;
    const size_t fixed = 256 + (size_t)N * 4 + (size_t)KK * DD * 2;
    const int nparts = (ws_size >= fixed + (size_t)B1 * KK * DD * 4) ? B1 : 1;

    hipMemsetAsync(loss, 0, 2 * sizeof(float), stream);
    if (nparts == 1) hipMemsetAsync(partial, 0, (size_t)KK * DD * 4, stream);

    k_stage1<<<B1, 1024, 0, stream>>>(X, labels, partial, x2g, spb1, nparts == 1 ? 1 : 0);
    k_stage2<<<KK, DD, 0, stream>>>(partial, nparts, centb);

    const int B3 = 256;
    k_stage3<<<B3, 512, 0, stream>>>(X, labels, x2g, centb, hbias, loss, N / B3);
    k_final<<<1, 64, 0, stream>>>(loss, out, 1.0f / (float)N);
}

// Round 2
// 482.360 us; speedup vs baseline: 1.3796x; 1.3796x over previous
//
#include <hip/hip_runtime.h>
#include <hip/hip_bf16.h>

#define DD 128
#define KK 256
#define TS 128
#define ROWB 136      // padded LDS row stride (bf16 elems) for MFMA fragment reads
#define SPB1 1024     // samples per stage-1 block (grid = N/SPB1 = 256)

typedef __attribute__((ext_vector_type(8))) short short8;
typedef __attribute__((ext_vector_type(4))) float f32x4;

static __device__ __forceinline__ unsigned short f2bf(float f) {
    unsigned int u = __float_as_uint(f);
    return (unsigned short)((u + 0x7fffu + ((u >> 16) & 1u)) >> 16);   // RNE
}
static __device__ __forceinline__ float bf2f(unsigned short h) {
    return __uint_as_float(((unsigned int)h) << 16);
}

// ---------------- stage 1: counting-sort gather, NO fp atomics ----------------
// MODE 0: write per-block partial slot + Xbf16 side-product
// MODE 1: write per-block partial slot only (ws too small for Xbf)
// MODE 2: global-atomic merge into partial[0] (ws tiny fallback)
template<int MODE>
__global__ __launch_bounds__(1024) void k_stage1_gather(
    const float* __restrict__ X, const int* __restrict__ labels,
    float* __restrict__ partial, unsigned int* __restrict__ Xbf)
{
    __shared__ int lab[SPB1];
    __shared__ int idx[SPB1];
    __shared__ int hist[KK];
    __shared__ int start[KK + 1];
    __shared__ int cursor[KK];

    const int tid  = threadIdx.x;
    const int lane = tid & 63;
    const int wave = tid >> 6;
    const int base = blockIdx.x * SPB1;

    if (tid < KK) hist[tid] = 0;
    __syncthreads();
    {
        const int l = labels[base + tid];
        lab[tid] = l;
        atomicAdd(&hist[l], 1);            // int LDS atomics, 1024/block total
    }
    __syncthreads();
    if (wave == 0) {                        // exclusive scan of 256 bins in one wave
        const int h0 = hist[4*lane], h1 = hist[4*lane+1];
        const int h2 = hist[4*lane+2], h3 = hist[4*lane+3];
        const int s = h0 + h1 + h2 + h3;
        int t = s;
#pragma unroll
        for (int d = 1; d < 64; d <<= 1) { const int u = __shfl_up(t, d); if (lane >= d) t += u; }
        const int e = t - s;
        start[4*lane]   = e;
        start[4*lane+1] = e + h0;
        start[4*lane+2] = e + h0 + h1;
        start[4*lane+3] = e + h0 + h1 + h2;
        if (lane == 63) start[KK] = t;
    }
    __syncthreads();
    if (tid < KK) cursor[tid] = start[tid];
    __syncthreads();
    {
        const int pos = atomicAdd(&cursor[lab[tid]], 1);
        idx[pos] = tid;
    }
    __syncthreads();

    // each wave gathers 16 clusters; lanes cover the 128 dims as float2
    for (int c = wave; c < KK; c += 16) {
        const int s0 = start[c], s1 = start[c + 1];
        float2 acc = make_float2(0.f, 0.f);
        if (s1 > s0) {
            int n0 = idx[s0];
            float2 v = *(const float2*)(X + (size_t)(base + n0) * DD + 2 * lane);
            for (int i = s0 + 1; i < s1; ++i) {          // software-pipelined: next load in flight
                const int n1 = idx[i];
                const float2 v1 = *(const float2*)(X + (size_t)(base + n1) * DD + 2 * lane);
                acc.x += v.x; acc.y += v.y;
                if (MODE == 0)
                    Xbf[(size_t)(base + n0) * (DD / 2) + lane] =
                        ((unsigned)f2bf(v.y) << 16) | (unsigned)f2bf(v.x);
                n0 = n1; v = v1;
            }
            acc.x += v.x; acc.y += v.y;
            if (MODE == 0)
                Xbf[(size_t)(base + n0) * (DD / 2) + lane] =
                    ((unsigned)f2bf(v.y) << 16) | (unsigned)f2bf(v.x);
        }
        if (MODE == 2) {
            atomicAdd(&partial[(size_t)c * DD + 2 * lane],     acc.x);
            atomicAdd(&partial[(size_t)c * DD + 2 * lane + 1], acc.y);
        } else {
            *(float2*)(partial + ((size_t)blockIdx.x * KK + c) * DD + 2 * lane) = acc;
        }
    }
}

// ---------------- stage 2: reduce partials, normalize (counts cancel), emit bf16 ----------------
__global__ void k_stage2(const float* __restrict__ partial, int nparts,
                         unsigned short* __restrict__ centb)
{
    const int k = blockIdx.x;       // cluster
    const int t = threadIdx.x;      // 512 threads
    const int d = t & (DD - 1);
    const int slice = t >> 7;       // 0..3
    float s = 0.f;
    for (int b = slice; b < nparts; b += 4)
        s += partial[((size_t)b * KK + k) * DD + d];
    __shared__ float red[4][DD];
    red[slice][d] = s;
    __syncthreads();
    float v = 0.f;
    if (t < DD) v = red[0][d] + red[1][d] + red[2][d] + red[3][d];
    float sq = v * v;
#pragma unroll
    for (int m = 32; m > 0; m >>= 1) sq += __shfl_xor(sq, m);
    __shared__ float wsum[8];
    if ((t & 63) == 0) wsum[t >> 6] = sq;
    __syncthreads();
    if (t < DD) centb[k * DD + d] = f2bf(v * rsqrtf(wsum[0] + wsum[1]));
}

// ---------------- stage 3: fused X@C^T (bf16 MFMA) + pos/neg loss ----------------
// BF16SRC=1 reads pre-converted Xbf (uint-packed bf16 pairs); BF16SRC=0 reads fp32 X and converts.
// x2 per sample is recomputed from the bf16 A-fragments (no x2g pass needed).
template<int BF16SRC>
__global__ __launch_bounds__(512, 1) void k_stage3(
    const float* __restrict__ Xf, const unsigned int* __restrict__ Xbf,
    const int* __restrict__ labels, const unsigned short* __restrict__ centb,
    const float* __restrict__ hbias, float* __restrict__ loss, int spb)
{
    __shared__ unsigned short Cl[KK * ROWB];  // 69632 B, row = cluster
    __shared__ unsigned short Xl[TS * ROWB];  // 34816 B, row = sample
    __shared__ int   labs[TS];
    __shared__ float lred[16];

    const int tid = threadIdx.x;
    const float hb = *hbias;
    const float bias = (hb > 20.f) ? hb : log1pf(__expf(hb));
    const float pos_bias = bias;
    const float neg_bias = 9.f * bias + 0.05f;

    const uint4* csrc = (const uint4*)centb;
    for (int c = tid; c < KK * DD / 8; c += 512) {
        const int row = c >> 4;
        const int col = (c & 15) << 3;
        *(uint4*)(&Cl[row * ROWB + col]) = csrc[c];
    }

    const int lane = tid & 63;
    const int wave = tid >> 6;
    const int m15  = lane & 15;
    const int q    = lane >> 4;
    const int kq   = q << 3;
    const int base = blockIdx.x * spb;
    float pos_acc = 0.f, neg_acc = 0.f;

    for (int t0 = 0; t0 < spb; t0 += TS) {
        __syncthreads();
        if (BF16SRC) {
            const uint4* xsrc = (const uint4*)(Xbf + (size_t)(base + t0) * (DD / 2));
            for (int c = tid; c < TS * DD / 8; c += 512) {   // 4 iters/thread
                const int row = c >> 4;
                const int col = (c & 15) << 3;
                *(uint4*)(&Xl[row * ROWB + col]) = xsrc[c];
            }
        } else {
            const float4* xsrc = (const float4*)(Xf + (size_t)(base + t0) * DD);
            for (int c = tid; c < TS * DD / 4; c += 512) {   // 8 iters/thread
                const int row = c >> 5;
                const int col = (c & 31) << 2;
                const float4 v = xsrc[c];
                ushort4 pk = make_ushort4(f2bf(v.x), f2bf(v.y), f2bf(v.z), f2bf(v.w));
                *(ushort4*)(&Xl[row * ROWB + col]) = pk;
            }
        }
        if (tid < TS) labs[tid] = labels[base + t0 + tid];
        __syncthreads();

        short8 afrag[4];
        const int arow = (wave << 4) + m15;
#pragma unroll
        for (int s = 0; s < 4; ++s)
            afrag[s] = *(const short8*)(&Xl[arow * ROWB + (s << 5) + kq]);

        // ||x||^2 for row m15 from the fragments (each lane holds 32 of 128 elems; sum over q)
        float x2p = 0.f;
#pragma unroll
        for (int s = 0; s < 4; ++s)
#pragma unroll
            for (int j = 0; j < 8; ++j) {
                const float e = bf2f((unsigned short)afrag[s][j]);
                x2p = fmaf(e, e, x2p);
            }
        x2p += __shfl_xor(x2p, 16);
        x2p += __shfl_xor(x2p, 32);   // now lane (q,m15) holds x2 of row m15

        f32x4 acc[16];
#pragma unroll
        for (int t = 0; t < 16; ++t) acc[t] = (f32x4){0.f, 0.f, 0.f, 0.f};
#pragma unroll
        for (int t = 0; t < 16; ++t) {
            const int brow = (t << 4) + m15;
#pragma unroll
            for (int s = 0; s < 4; ++s) {
                const short8 bfrag = *(const short8*)(&Cl[brow * ROWB + (s << 5) + kq]);
                acc[t] = __builtin_amdgcn_mfma_f32_16x16x32_bf16(afrag[s], bfrag, acc[t], 0, 0, 0);
            }
        }

#pragma unroll
        for (int r = 0; r < 4; ++r) {
            const int ml = (wave << 4) + (q << 2) + r;
            const int l  = labs[ml];
            const float x2 = __shfl(x2p, (q << 2) + r, 16);  // x2 of row (q*4+r) lives in lane m15=(q*4+r)
            float posd = -1e30f, negd = -1e30f;
#pragma unroll
            for (int t = 0; t < 16; ++t) {
                const int cl = (t << 4) + m15;
                const float v = acc[t][r];
                const bool isp = (cl == l);
                posd = isp ? v : posd;
                negd = isp ? negd : fmaxf(negd, v);
            }
#pragma unroll
            for (int m = 1; m < 16; m <<= 1) {
                posd = fmaxf(posd, __shfl_xor(posd, m));
                negd = fmaxf(negd, __shfl_xor(negd, m));
            }
            if (m15 == 0) {
                const float pd = x2 + 1.0f - 2.f * posd;   // ||c||^2 == 1 (normalized)
                const float nd = x2 + 1.0f - 2.f * negd;   // min dist <=> max dot
                pos_acc += fmaxf(pd - pos_bias, 0.f);
                neg_acc += fmaxf(neg_bias - nd, 0.f);
            }
        }
    }

#pragma unroll
    for (int m = 32; m > 0; m >>= 1) {
        pos_acc += __shfl_xor(pos_acc, m);
        neg_acc += __shfl_xor(neg_acc, m);
    }
    if (lane == 0) { lred[wave] = pos_acc; lred[8 + wave] = neg_acc; }
    __syncthreads();
    if (tid == 0) {
        float p = 0.f, n = 0.f;
#pragma unroll
        for (int w = 0; w < 8; ++w) { p += lred[w]; n += lred[8 + w]; }
        atomicAdd(&loss[0], p);
        atomicAdd(&loss[1], n);
    }
}

__global__ void k_final(const float* __restrict__ loss, float* __restrict__ out, float invN)
{
    if (threadIdx.x == 0) {
        out[0] = 4.0f * loss[0] * invN;
        out[1] = loss[1] * invN;
    }
}

extern "C" void kernel_launch(void* const* d_in, const int* in_sizes, int n_in,
                              void* d_out, int out_size, void* d_ws, size_t ws_size,
                              hipStream_t stream)
{
    const float* X      = (const float*)d_in[0];
    // d_in[1] (scores) is dead in the reference forward — never read.
    const int*   labels = (const int*)d_in[2];
    const float* hbias  = (const float*)d_in[3];
    float* out = (float*)d_out;
    const int N = in_sizes[0] / DD;
    const int G = N / SPB1;                   // 256 stage-1/3 blocks

    char* ws = (char*)d_ws;
    const size_t offC   = 256;
    const size_t offXbf = offC + (size_t)KK * DD * 2;          // 256 + 64 KiB
    const size_t szXbf  = (size_t)N * DD * 2;                  // 64 MiB
    const size_t szPart = (size_t)G * KK * DD * 4;             // 32 MiB

    float*          loss  = (float*)ws;
    unsigned short* centb = (unsigned short*)(ws + offC);

    int mode;
    float* partial;
    unsigned int* Xbf = nullptr;
    if (ws_size >= offXbf + szXbf + szPart) {
        mode = 0; Xbf = (unsigned int*)(ws + offXbf);
        partial = (float*)(ws + offXbf + szXbf);
    } else if (ws_size >= offXbf + szPart) {
        mode = 1; partial = (float*)(ws + offXbf);
    } else {
        mode = 2; partial = (float*)(ws + offXbf);
    }
    const int nparts = (mode == 2) ? 1 : G;

    hipMemsetAsync(loss, 0, 2 * sizeof(float), stream);
    if (mode == 2) hipMemsetAsync(partial, 0, (size_t)KK * DD * 4, stream);

    if (mode == 0)      k_stage1_gather<0><<<G, 1024, 0, stream>>>(X, labels, partial, Xbf);
    else if (mode == 1) k_stage1_gather<1><<<G, 1024, 0, stream>>>(X, labels, partial, nullptr);
    else                k_stage1_gather<2><<<G, 1024, 0, stream>>>(X, labels, partial, nullptr);

    k_stage2<<<KK, 512, 0, stream>>>(partial, nparts, centb);

    if (mode == 0) k_stage3<1><<<G, 512, 0, stream>>>(nullptr, Xbf, labels, centb, hbias, loss, N / G);
    else           k_stage3<0><<<G, 512, 0, stream>>>(X, nullptr, labels, centb, hbias, loss, N / G);

    k_final<<<1, 64, 0, stream>>>(loss, out, 1.0f / (float)N);
}

// Round 3
// 479.944 us; speedup vs baseline: 1.3865x; 1.0050x over previous
//
#include <hip/hip_runtime.h>
#include <hip/hip_bf16.h>

#define DD 128
#define KK 256
#define TS 256        // samples per stage-3 tile (16 waves x 16 rows)
#define ROWB 136      // padded LDS row stride (bf16 elems): dword-bank pattern is uniform 8/bank for b128
#define SPB1 1024     // samples per stage-1 block (grid = N/SPB1 = 256)

typedef __attribute__((ext_vector_type(8))) short short8;
typedef __attribute__((ext_vector_type(4))) float f32x4;

static __device__ __forceinline__ unsigned short f2bf(float f) {
    unsigned int u = __float_as_uint(f);
    return (unsigned short)((u + 0x7fffu + ((u >> 16) & 1u)) >> 16);   // RNE
}
static __device__ __forceinline__ float bf2f(unsigned short h) {
    return __uint_as_float(((unsigned int)h) << 16);
}

// ---------------- stage 1: counting-sort gather, NO fp atomics ----------------
// MODE 0: write per-block partial slot.  MODE 2: global-atomic merge (tiny-ws fallback).
template<int MODE>
__global__ __launch_bounds__(1024) void k_stage1_gather(
    const float* __restrict__ X, const int* __restrict__ labels,
    float* __restrict__ partial)
{
    __shared__ int lab[SPB1];
    __shared__ int idx[SPB1];
    __shared__ int hist[KK];
    __shared__ int start[KK + 1];
    __shared__ int cursor[KK];

    const int tid  = threadIdx.x;
    const int lane = tid & 63;
    const int wave = tid >> 6;
    const int base = blockIdx.x * SPB1;

    if (tid < KK) hist[tid] = 0;
    __syncthreads();
    {
        const int l = labels[base + tid];
        lab[tid] = l;
        atomicAdd(&hist[l], 1);            // int LDS atomics, 1024/block
    }
    __syncthreads();
    if (wave == 0) {                        // exclusive scan of 256 bins in one wave
        const int h0 = hist[4*lane], h1 = hist[4*lane+1];
        const int h2 = hist[4*lane+2], h3 = hist[4*lane+3];
        const int s = h0 + h1 + h2 + h3;
        int t = s;
#pragma unroll
        for (int d = 1; d < 64; d <<= 1) { const int u = __shfl_up(t, d); if (lane >= d) t += u; }
        const int e = t - s;
        start[4*lane]   = e;
        start[4*lane+1] = e + h0;
        start[4*lane+2] = e + h0 + h1;
        start[4*lane+3] = e + h0 + h1 + h2;
        if (lane == 63) start[KK] = t;
    }
    __syncthreads();
    if (tid < KK) cursor[tid] = start[tid];
    __syncthreads();
    {
        const int pos = atomicAdd(&cursor[lab[tid]], 1);
        idx[pos] = tid;
    }
    __syncthreads();

    // each wave gathers 16 clusters; lanes cover the 128 dims as float2
    for (int c = wave; c < KK; c += 16) {
        const int s0 = start[c], s1 = start[c + 1];
        float2 acc = make_float2(0.f, 0.f);
        if (s1 > s0) {
            int n0 = idx[s0];
            float2 v = *(const float2*)(X + (size_t)(base + n0) * DD + 2 * lane);
            for (int i = s0 + 1; i < s1; ++i) {
                const int n1 = idx[i];
                const float2 v1 = *(const float2*)(X + (size_t)(base + n1) * DD + 2 * lane);
                acc.x += v.x; acc.y += v.y;
                n0 = n1; v = v1;
            }
            acc.x += v.x; acc.y += v.y;
        }
        if (MODE == 2) {
            atomicAdd(&partial[(size_t)c * DD + 2 * lane],     acc.x);
            atomicAdd(&partial[(size_t)c * DD + 2 * lane + 1], acc.y);
        } else {
            *(float2*)(partial + ((size_t)blockIdx.x * KK + c) * DD + 2 * lane) = acc;
        }
    }
}

// ---------------- stage 2: reduce partials, normalize (counts cancel), emit bf16 ----------------
__global__ void k_stage2(const float* __restrict__ partial, int nparts,
                         unsigned short* __restrict__ centb)
{
    const int k = blockIdx.x;       // cluster
    const int t = threadIdx.x;      // 512 threads
    const int d = t & (DD - 1);
    const int slice = t >> 7;       // 0..3
    float s = 0.f;
    for (int b = slice; b < nparts; b += 4)
        s += partial[((size_t)b * KK + k) * DD + d];
    __shared__ float red[4][DD];
    red[slice][d] = s;
    __syncthreads();
    float v = 0.f;
    if (t < DD) v = red[0][d] + red[1][d] + red[2][d] + red[3][d];
    float sq = v * v;
#pragma unroll
    for (int m = 32; m > 0; m >>= 1) sq += __shfl_xor(sq, m);
    __shared__ float wsum[8];
    if ((t & 63) == 0) wsum[t >> 6] = sq;
    __syncthreads();
    if (t < DD) centb[k * DD + d] = f2bf(v * rsqrtf(wsum[0] + wsum[1]));
}

// ---------------- stage 3: fused X@C^T (bf16 MFMA) + pos/neg loss ----------------
// 1024 threads (16 waves = 4/SIMD), TS=256 sample tile, fp32 X source (L3-warm re-read).
__global__ __launch_bounds__(1024, 4) void k_stage3(
    const float* __restrict__ Xf, const int* __restrict__ labels,
    const unsigned short* __restrict__ centb,
    const float* __restrict__ hbias, float* __restrict__ loss, int spb)
{
    __shared__ unsigned short Cl[KK * ROWB];  // 69632 B, row = cluster
    __shared__ unsigned short Xl[TS * ROWB];  // 69632 B, row = sample
    __shared__ int   labs[TS];
    __shared__ float lred[32];

    const int tid = threadIdx.x;
    const float hb = *hbias;
    const float bias = (hb > 20.f) ? hb : log1pf(__expf(hb));
    const float pos_bias = bias;
    const float neg_bias = 9.f * bias + 0.05f;

    const uint4* csrc = (const uint4*)centb;
    for (int c = tid; c < KK * DD / 8; c += 1024) {  // 4 iters/thread
        const int row = c >> 4;
        const int col = (c & 15) << 3;
        *(uint4*)(&Cl[row * ROWB + col]) = csrc[c];
    }

    const int lane = tid & 63;
    const int wave = tid >> 6;       // 0..15
    const int m15  = lane & 15;
    const int q    = lane >> 4;
    const int kq   = q << 3;
    const int base = blockIdx.x * spb;
    float pos_acc = 0.f, neg_acc = 0.f;

    for (int t0 = 0; t0 < spb; t0 += TS) {
        __syncthreads();  // protects Xl reuse (and Cl staging on iter 0)
        const float4* xsrc = (const float4*)(Xf + (size_t)(base + t0) * DD);
        for (int c = tid; c < TS * DD / 4; c += 1024) {   // 8 iters/thread
            const int row = c >> 5;
            const int col = (c & 31) << 2;
            const float4 v = xsrc[c];
            ushort4 pk = make_ushort4(f2bf(v.x), f2bf(v.y), f2bf(v.z), f2bf(v.w));
            *(ushort4*)(&Xl[row * ROWB + col]) = pk;
        }
        if (tid < TS) labs[tid] = labels[base + t0 + tid];
        __syncthreads();

        short8 afrag[4];
        const int arow = (wave << 4) + m15;
#pragma unroll
        for (int s = 0; s < 4; ++s)
            afrag[s] = *(const short8*)(&Xl[arow * ROWB + (s << 5) + kq]);

        // ||x||^2 of row m15 from the bf16 fragments (sum over q-halves)
        float x2p = 0.f;
#pragma unroll
        for (int s = 0; s < 4; ++s)
#pragma unroll
            for (int j = 0; j < 8; ++j) {
                const float e = bf2f((unsigned short)afrag[s][j]);
                x2p = fmaf(e, e, x2p);
            }
        x2p += __shfl_xor(x2p, 16);
        x2p += __shfl_xor(x2p, 32);

        f32x4 acc[16];
#pragma unroll
        for (int t = 0; t < 16; ++t) acc[t] = (f32x4){0.f, 0.f, 0.f, 0.f};
#pragma unroll
        for (int t = 0; t < 16; ++t) {
            const int brow = (t << 4) + m15;
#pragma unroll
            for (int s = 0; s < 4; ++s) {
                const short8 bfrag = *(const short8*)(&Cl[brow * ROWB + (s << 5) + kq]);
                acc[t] = __builtin_amdgcn_mfma_f32_16x16x32_bf16(afrag[s], bfrag, acc[t], 0, 0, 0);
            }
        }

        // D layout: col=lane&15 (cluster), row=q*4+r (sample within wave tile)
#pragma unroll
        for (int r = 0; r < 4; ++r) {
            const int ml = (wave << 4) + (q << 2) + r;
            const int l  = labs[ml];
            const float x2 = __shfl(x2p, (q << 2) + r, 16);
            float posd = -1e30f, negd = -1e30f;
#pragma unroll
            for (int t = 0; t < 16; ++t) {
                const int cl = (t << 4) + m15;
                const float v = acc[t][r];
                const bool isp = (cl == l);
                posd = isp ? v : posd;
                negd = isp ? negd : fmaxf(negd, v);
            }
#pragma unroll
            for (int m = 1; m < 16; m <<= 1) {
                posd = fmaxf(posd, __shfl_xor(posd, m));
                negd = fmaxf(negd, __shfl_xor(negd, m));
            }
            if (m15 == 0) {
                const float pd = x2 + 1.0f - 2.f * posd;   // ||c||^2 == 1 (normalized)
                const float nd = x2 + 1.0f - 2.f * negd;   // min dist <=> max dot
                pos_acc += fmaxf(pd - pos_bias, 0.f);
                neg_acc += fmaxf(neg_bias - nd, 0.f);
            }
        }
    }

#pragma unroll
    for (int m = 32; m > 0; m >>= 1) {
        pos_acc += __shfl_xor(pos_acc, m);
        neg_acc += __shfl_xor(neg_acc, m);
    }
    if (lane == 0) { lred[wave] = pos_acc; lred[16 + wave] = neg_acc; }
    __syncthreads();
    if (tid == 0) {
        float p = 0.f, n = 0.f;
#pragma unroll
        for (int w = 0; w < 16; ++w) { p += lred[w]; n += lred[16 + w]; }
        atomicAdd(&loss[0], p);
        atomicAdd(&loss[1], n);
    }
}

__global__ void k_final(const float* __restrict__ loss, float* __restrict__ out, float invN)
{
    if (threadIdx.x == 0) {
        out[0] = 4.0f * loss[0] * invN;
        out[1] = loss[1] * invN;
    }
}

extern "C" void kernel_launch(void* const* d_in, const int* in_sizes, int n_in,
                              void* d_out, int out_size, void* d_ws, size_t ws_size,
                              hipStream_t stream)
{
    const float* X      = (const float*)d_in[0];
    // d_in[1] (scores) is dead in the reference forward — never read.
    const int*   labels = (const int*)d_in[2];
    const float* hbias  = (const float*)d_in[3];
    float* out = (float*)d_out;
    const int N = in_sizes[0] / DD;
    const int G = N / SPB1;                   // 256 blocks

    char* ws = (char*)d_ws;
    const size_t offC    = 256;
    const size_t offPart = offC + (size_t)KK * DD * 2;         // 256 + 64 KiB
    const size_t szPart  = (size_t)G * KK * DD * 4;            // 32 MiB

    float*          loss    = (float*)ws;
    unsigned short* centb   = (unsigned short*)(ws + offC);
    float*          partial = (float*)(ws + offPart);

    const int mode   = (ws_size >= offPart + szPart) ? 0 : 2;
    const int nparts = (mode == 2) ? 1 : G;

    hipMemsetAsync(loss, 0, 2 * sizeof(float), stream);
    if (mode == 2) hipMemsetAsync(partial, 0, (size_t)KK * DD * 4, stream);

    if (mode == 0) k_stage1_gather<0><<<G, 1024, 0, stream>>>(X, labels, partial);
    else           k_stage1_gather<2><<<G, 1024, 0, stream>>>(X, labels, partial);

    k_stage2<<<KK, 512, 0, stream>>>(partial, nparts, centb);

    k_stage3<<<G, 1024, 0, stream>>>(X, labels, centb, hbias, loss, N / G);

    k_final<<<1, 64, 0, stream>>>(loss, out, 1.0f / (float)N);
}